// Round 4
// baseline (523.707 us; speedup 1.0000x reference)
//
#include <hip/hip_runtime.h>
#include <hip/hip_bf16.h>

typedef __bf16 bf16;
typedef bf16  bf16x8 __attribute__((ext_vector_type(8)));
typedef float f32x4  __attribute__((ext_vector_type(4)));

union B8 { bf16x8 v; bf16 e[8]; };
union F4 { f32x4 v; float e[4]; };

// ---------------------------------------------------------------------------
// Kernel 1: GroupNorm. fp32 in, bf16 out (xn feeds bf16 MFMA GEMM).
// One block per (b, group); group = contiguous 32 ch x 1024 T fp32 slab.
// ---------------------------------------------------------------------------
__global__ __launch_bounds__(256) void gn_kernel(
    const float* __restrict__ x, const float* __restrict__ w,
    const float* __restrict__ bias, bf16* __restrict__ xn)
{
  const int blk = blockIdx.x;
  const int b = blk >> 5, g = blk & 31;
  const size_t base = (size_t)(b * 1024 + g * 32) * 1024;
  const float* xp = x + base;
  bf16* op = xn + base;
  const int tid = threadIdx.x;

  float s = 0.f, ss = 0.f;
  for (int ch = tid; ch < 4096; ch += 256) {           // 4096 chunks of 8 floats
    const float4* p = (const float4*)(xp + (size_t)ch * 8);
    float4 u0 = p[0], u1 = p[1];
    s  += u0.x + u0.y + u0.z + u0.w + u1.x + u1.y + u1.z + u1.w;
    ss += u0.x*u0.x + u0.y*u0.y + u0.z*u0.z + u0.w*u0.w
        + u1.x*u1.x + u1.y*u1.y + u1.z*u1.z + u1.w*u1.w;
  }
  #pragma unroll
  for (int m = 1; m < 64; m <<= 1) { s += __shfl_xor(s, m); ss += __shfl_xor(ss, m); }

  __shared__ float red[8];
  __shared__ float stats[2];
  const int wave = tid >> 6, lane = tid & 63;
  if (lane == 0) { red[wave] = s; red[4 + wave] = ss; }
  __syncthreads();
  if (tid == 0) {
    float ts  = red[0] + red[1] + red[2] + red[3];
    float tss = red[4] + red[5] + red[6] + red[7];
    float mu  = ts * (1.f / 32768.f);
    float var = tss * (1.f / 32768.f) - mu * mu;
    stats[0] = mu;
    stats[1] = rsqrtf(var + 1e-5f);
  }
  __syncthreads();
  const float mu = stats[0], rs = stats[1];

  for (int ch = tid; ch < 4096; ch += 256) {
    const int c = ch >> 7;                              // local channel 0..31
    const float wt = w[g * 32 + c] * rs;
    const float bs = bias[g * 32 + c];
    const float4* p = (const float4*)(xp + (size_t)ch * 8);
    float4 u0 = p[0], u1 = p[1];
    B8 o;
    o.e[0] = (bf16)((u0.x - mu) * wt + bs);
    o.e[1] = (bf16)((u0.y - mu) * wt + bs);
    o.e[2] = (bf16)((u0.z - mu) * wt + bs);
    o.e[3] = (bf16)((u0.w - mu) * wt + bs);
    o.e[4] = (bf16)((u1.x - mu) * wt + bs);
    o.e[5] = (bf16)((u1.y - mu) * wt + bs);
    o.e[6] = (bf16)((u1.z - mu) * wt + bs);
    o.e[7] = (bf16)((u1.w - mu) * wt + bs);
    *(bf16x8*)(op + (size_t)ch * 8) = o.v;
  }
}

// ---------------------------------------------------------------------------
// Kernel 2/4: GEMM  C[m][n] = sum_k Aw[m][k]*B[k][n] (+bias[m]) (+res[m][n])
// Aw: fp32 weights (M x K), converted to bf16 during LDS staging.
// Bm: bf16 (K x N). Output: bf16 (Cb) or fp32 (Cf, with fp32 residual).
// 64x64 tile, 4 waves 2x2, BK=32, 16x16x32 MFMA. LDS row stride 48 elems
// = 96 B (multiple of 16 B -> ds b128 alignment-safe).
// ---------------------------------------------------------------------------
__global__ __launch_bounds__(256) void gemm_kernel(
    const float* __restrict__ Aw, const bf16* __restrict__ Bm,
    bf16* __restrict__ Cb, float* __restrict__ Cf,
    const float* __restrict__ bias, const float* __restrict__ resf,
    int M, int N, int K)
{
  const int n0 = blockIdx.x * 64, m0 = blockIdx.y * 64;

  __shared__ __align__(16) bf16 Al[64][48];   // [m][k]
  __shared__ __align__(16) bf16 Bl[64][48];   // [n][k] (transposed)

  const int tid  = threadIdx.x;
  const int wave = tid >> 6, lane = tid & 63;
  const int quad = lane >> 4, l15 = lane & 15;
  const int wr = wave >> 1, wc = wave & 1;

  F4 acc[2][2];
  #pragma unroll
  for (int i = 0; i < 2; ++i)
    #pragma unroll
    for (int j = 0; j < 2; ++j) acc[i][j].v = (f32x4){0.f, 0.f, 0.f, 0.f};

  const int am = tid >> 2, ako = (tid & 3) * 8;   // A: 8 fp32/thread -> bf16
  const int bk = tid >> 3, bno = (tid & 7) * 8;   // B: 8 bf16/thread

  for (int k0 = 0; k0 < K; k0 += 32) {
    {
      const float4* ap = (const float4*)(Aw + (size_t)(m0 + am) * K + k0 + ako);
      float4 a0 = ap[0], a1 = ap[1];
      B8 av;
      av.e[0] = (bf16)a0.x; av.e[1] = (bf16)a0.y;
      av.e[2] = (bf16)a0.z; av.e[3] = (bf16)a0.w;
      av.e[4] = (bf16)a1.x; av.e[5] = (bf16)a1.y;
      av.e[6] = (bf16)a1.z; av.e[7] = (bf16)a1.w;
      *(bf16x8*)&Al[am][ako] = av.v;
    }
    B8 bv; bv.v = *(const bf16x8*)(Bm + (size_t)(k0 + bk) * N + n0 + bno);
    #pragma unroll
    for (int j = 0; j < 8; ++j) Bl[bno + j][bk] = bv.e[j];   // transpose to [n][k]
    __syncthreads();

    bf16x8 af[2], bfr[2];
    #pragma unroll
    for (int mt = 0; mt < 2; ++mt)
      af[mt] = *(const bf16x8*)&Al[wr * 32 + mt * 16 + l15][quad * 8];
    #pragma unroll
    for (int nt = 0; nt < 2; ++nt)
      bfr[nt] = *(const bf16x8*)&Bl[wc * 32 + nt * 16 + l15][quad * 8];
    #pragma unroll
    for (int mt = 0; mt < 2; ++mt)
      #pragma unroll
      for (int nt = 0; nt < 2; ++nt)
        acc[mt][nt].v = __builtin_amdgcn_mfma_f32_16x16x32_bf16(
            af[mt], bfr[nt], acc[mt][nt].v, 0, 0, 0);
    __syncthreads();
  }

  // Epilogue: C/D layout col=lane&15, row=quad*4+r
  #pragma unroll
  for (int mt = 0; mt < 2; ++mt) {
    #pragma unroll
    for (int r = 0; r < 4; ++r) {
      const int m = m0 + wr * 32 + mt * 16 + quad * 4 + r;
      const float bb = bias[m];
      #pragma unroll
      for (int nt = 0; nt < 2; ++nt) {
        const int n = n0 + wc * 32 + nt * 16 + l15;
        float v = acc[mt][nt].e[r] + bb;
        if (resf) v += resf[(size_t)m * N + n];
        if (Cf) Cf[(size_t)m * N + n] = v;
        else    Cb[(size_t)m * N + n] = (bf16)v;
      }
    }
  }
}

// ---------------------------------------------------------------------------
// Kernel 3: attention for one (h, 64-row t-tile) of one batch (qkv pointer
// pre-offset). qkv rows: o = h*192 + {0:q, 64:k, 128:v} + c; all bf16.
// Flash-style online softmax over s-chunks of 64; wave w owns t rows
// [w*16, w*16+16). LDS row stride 72 elems = 144 B (16 B multiple).
// ---------------------------------------------------------------------------
__global__ __launch_bounds__(256) void attn_kernel(
    const bf16* __restrict__ qkv, bf16* __restrict__ aout)
{
  const int tt = blockIdx.x, h = blockIdx.y;
  const int t0 = tt * 64;
  const size_t headbase = (size_t)(h * 192) * 1024;
  const bf16* qp = qkv + headbase;
  const bf16* kp = qkv + headbase + 64 * 1024;
  const bf16* vp = qkv + headbase + 128 * 1024;

  __shared__ __align__(16) bf16 qT[64][72];   // [t][c]
  __shared__ __align__(16) bf16 kT[64][72];   // [s][c]
  __shared__ __align__(16) bf16 Pl[64][72];   // [t][s]
  __shared__ __align__(16) bf16 ol[64][72];   // [c][t]

  const int tid  = threadIdx.x;
  const int wave = tid >> 6, lane = tid & 63;
  const int quad = lane >> 4, l15 = lane & 15;

  {
    const int c = tid >> 2, to = (tid & 3) * 16;
    #pragma unroll
    for (int hh = 0; hh < 2; ++hh) {
      B8 u; u.v = *(const bf16x8*)(qp + (size_t)c * 1024 + t0 + to + hh * 8);
      #pragma unroll
      for (int j = 0; j < 8; ++j) qT[to + hh * 8 + j][c] = u.e[j];
    }
  }

  float m_i[4], l_i[4], alpha[4];
  #pragma unroll
  for (int r = 0; r < 4; ++r) { m_i[r] = -__builtin_inff(); l_i[r] = 0.f; }
  F4 oacc[4];
  #pragma unroll
  for (int ct = 0; ct < 4; ++ct) oacc[ct].v = (f32x4){0.f, 0.f, 0.f, 0.f};

  for (int s0 = 0; s0 < 1024; s0 += 64) {
    {
      const int c = tid >> 2, so = (tid & 3) * 16;
      #pragma unroll
      for (int hh = 0; hh < 2; ++hh) {
        B8 u; u.v = *(const bf16x8*)(kp + (size_t)c * 1024 + s0 + so + hh * 8);
        #pragma unroll
        for (int j = 0; j < 8; ++j) kT[so + hh * 8 + j][c] = u.e[j];
      }
    }
    __syncthreads();

    F4 sacc[4];
    #pragma unroll
    for (int st = 0; st < 4; ++st) sacc[st].v = (f32x4){0.f, 0.f, 0.f, 0.f};
    const bf16x8 aq0 = *(const bf16x8*)&qT[wave * 16 + l15][quad * 8];
    const bf16x8 aq1 = *(const bf16x8*)&qT[wave * 16 + l15][32 + quad * 8];
    #pragma unroll
    for (int st = 0; st < 4; ++st) {
      const bf16x8 bk0 = *(const bf16x8*)&kT[st * 16 + l15][quad * 8];
      const bf16x8 bk1 = *(const bf16x8*)&kT[st * 16 + l15][32 + quad * 8];
      sacc[st].v = __builtin_amdgcn_mfma_f32_16x16x32_bf16(aq0, bk0, sacc[st].v, 0, 0, 0);
      sacc[st].v = __builtin_amdgcn_mfma_f32_16x16x32_bf16(aq1, bk1, sacc[st].v, 0, 0, 0);
    }
    #pragma unroll
    for (int st = 0; st < 4; ++st)
      #pragma unroll
      for (int r = 0; r < 4; ++r) sacc[st].e[r] *= 0.125f;   // 1/sqrt(64)

    #pragma unroll
    for (int r = 0; r < 4; ++r) {
      float mx = fmaxf(fmaxf(sacc[0].e[r], sacc[1].e[r]),
                       fmaxf(sacc[2].e[r], sacc[3].e[r]));
      #pragma unroll
      for (int mk = 1; mk < 16; mk <<= 1) mx = fmaxf(mx, __shfl_xor(mx, mk));
      const float mnew = fmaxf(m_i[r], mx);
      float sum = 0.f;
      #pragma unroll
      for (int st = 0; st < 4; ++st) {
        const float p = __expf(sacc[st].e[r] - mnew);
        sacc[st].e[r] = p;
        sum += p;
      }
      #pragma unroll
      for (int mk = 1; mk < 16; mk <<= 1) sum += __shfl_xor(sum, mk);
      const float a = __expf(m_i[r] - mnew);
      l_i[r] = l_i[r] * a + sum;
      m_i[r] = mnew;
      alpha[r] = a;
    }
    #pragma unroll
    for (int ct = 0; ct < 4; ++ct)
      #pragma unroll
      for (int r = 0; r < 4; ++r) oacc[ct].e[r] *= alpha[r];

    #pragma unroll
    for (int st = 0; st < 4; ++st)
      #pragma unroll
      for (int r = 0; r < 4; ++r)
        Pl[wave * 16 + quad * 4 + r][st * 16 + l15] = (bf16)sacc[st].e[r];
    __syncthreads();

    #pragma unroll
    for (int ks = 0; ks < 2; ++ks) {
      const bf16x8 ap = *(const bf16x8*)&Pl[wave * 16 + l15][ks * 32 + quad * 8];
      #pragma unroll
      for (int ct = 0; ct < 4; ++ct) {
        const bf16x8 bv = *(const bf16x8*)(vp + (size_t)(ct * 16 + l15) * 1024
                                              + s0 + ks * 32 + quad * 8);
        oacc[ct].v = __builtin_amdgcn_mfma_f32_16x16x32_bf16(ap, bv, oacc[ct].v, 0, 0, 0);
      }
    }
    __syncthreads();
  }

  #pragma unroll
  for (int r = 0; r < 4; ++r) {
    const float inv = 1.f / l_i[r];
    #pragma unroll
    for (int ct = 0; ct < 4; ++ct)
      ol[ct * 16 + l15][wave * 16 + quad * 4 + r] = (bf16)(oacc[ct].e[r] * inv);
  }
  __syncthreads();
  {
    const int c = tid >> 2, to = (tid & 3) * 16;
    bf16* dst = aout + (size_t)(h * 64 + c) * 1024 + t0 + to;
    #pragma unroll
    for (int hh = 0; hh < 2; ++hh)
      *(bf16x8*)(dst + hh * 8) = *(const bf16x8*)&ol[c][to + hh * 8];
  }
}

// ---------------------------------------------------------------------------
// fp32 I/O per the reference (setup_inputs is all jnp.float32). Internal
// compute in bf16 MFMA (harness threshold 2%*max allows bf16 precision).
// Memory plan:
//   xn (bf16, 8 MB)  -> first half of d_out (fp32 out = 16 MB). Batches run
//                       3,2,1,0 so proj's fp32 writes only clobber consumed
//                       xn slices.
//   qkv_b (bf16,6MB) -> ws[0,6MB); a_b (bf16,2MB) -> ws[6,8MB). ws use: 8 MB.
// ---------------------------------------------------------------------------
extern "C" void kernel_launch(void* const* d_in, const int* in_sizes, int n_in,
                              void* d_out, int out_size, void* d_ws, size_t ws_size,
                              hipStream_t stream)
{
  const float* x    = (const float*)d_in[0];
  const float* nw   = (const float*)d_in[1];
  const float* nb   = (const float*)d_in[2];
  const float* qkvw = (const float*)d_in[3];
  const float* qkvb = (const float*)d_in[4];
  const float* pw   = (const float*)d_in[5];
  const float* pb   = (const float*)d_in[6];
  float* out = (float*)d_out;

  bf16* xn   = (bf16*)d_out;                               // 4M bf16 = 8 MB
  bf16* qkvB = (bf16*)d_ws;                                // 3M bf16 = 6 MB
  bf16* aB   = (bf16*)d_ws + (size_t)3 * 1024 * 1024;      // 1M bf16 = 2 MB

  // 1) GroupNorm -> xn (bf16, in low half of d_out)
  gn_kernel<<<dim3(128), dim3(256), 0, stream>>>(x, nw, nb, xn);

  // 2-4) Per batch (reverse order for the d_out alias): QKV -> attn -> proj
  for (int b = 3; b >= 0; --b) {
    const size_t off = (size_t)b * 1024 * 1024;
    gemm_kernel<<<dim3(16, 48, 1), dim3(256), 0, stream>>>(
        qkvw, xn + off, qkvB, nullptr, qkvb, nullptr, 3072, 1024, 1024);
    attn_kernel<<<dim3(16, 16, 1), dim3(256), 0, stream>>>(qkvB, aB);
    gemm_kernel<<<dim3(16, 16, 1), dim3(256), 0, stream>>>(
        pw, aB, nullptr, out + off, pb, x + off, 1024, 1024, 1024);
  }
}

// Round 5
// 289.427 us; speedup vs baseline: 1.8095x; 1.8095x over previous
//
#include <hip/hip_runtime.h>
#include <hip/hip_bf16.h>

typedef __bf16 bf16;
typedef bf16  bf16x4 __attribute__((ext_vector_type(4)));
typedef bf16  bf16x8 __attribute__((ext_vector_type(8)));
typedef float f32x4  __attribute__((ext_vector_type(4)));

union B8 { bf16x8 v; bf16 e[8]; };
union B4 { bf16x4 v; bf16 e[4]; };
union F4 { f32x4 v; float e[4]; };

// ---------------------------------------------------------------------------
// Kernel 1: GroupNorm, TRANSPOSED output: x[b][c][t] fp32 -> xnt[b][t][c] bf16.
// One block per (b, group); group = contiguous 32ch x 1024t fp32 slab.
// Transposed xnt makes the QKV GEMM's B-operand staging a pure vector copy.
// ---------------------------------------------------------------------------
__global__ __launch_bounds__(256) void gn_t_kernel(
    const float* __restrict__ x, const float* __restrict__ w,
    const float* __restrict__ bias, bf16* __restrict__ xnt)
{
  const int blk = blockIdx.x;
  const int b = blk >> 5, g = blk & 31;
  const float* xp = x + (size_t)(b * 1024 + g * 32) * 1024;
  const int tid = threadIdx.x;

  float s = 0.f, ss = 0.f;
  for (int ch = tid; ch < 4096; ch += 256) {           // 4096 chunks of 8 floats
    const float4* p = (const float4*)(xp + (size_t)ch * 8);
    float4 u0 = p[0], u1 = p[1];
    s  += u0.x + u0.y + u0.z + u0.w + u1.x + u1.y + u1.z + u1.w;
    ss += u0.x*u0.x + u0.y*u0.y + u0.z*u0.z + u0.w*u0.w
        + u1.x*u1.x + u1.y*u1.y + u1.z*u1.z + u1.w*u1.w;
  }
  #pragma unroll
  for (int m = 1; m < 64; m <<= 1) { s += __shfl_xor(s, m); ss += __shfl_xor(ss, m); }

  __shared__ float red[8];
  __shared__ float stats[2];
  const int wave = tid >> 6, lane = tid & 63;
  if (lane == 0) { red[wave] = s; red[4 + wave] = ss; }
  __syncthreads();
  if (tid == 0) {
    float ts  = red[0] + red[1] + red[2] + red[3];
    float tss = red[4] + red[5] + red[6] + red[7];
    float mu  = ts * (1.f / 32768.f);
    float var = tss * (1.f / 32768.f) - mu * mu;
    stats[0] = mu;
    stats[1] = rsqrtf(var + 1e-5f);
  }
  __syncthreads();
  const float mu = stats[0], rs = stats[1];

  // Pass 2: thread owns column t; reads x[c][t] (coalesced across lanes),
  // writes 32 contiguous bf16 (64 B) to xnt[b*1024+t][g*32 .. g*32+31].
  for (int ti = 0; ti < 4; ++ti) {
    const int t = ti * 256 + tid;
    B8 o[4];
    #pragma unroll
    for (int cc = 0; cc < 32; ++cc) {
      const float wt = w[g * 32 + cc] * rs;
      const float bs = bias[g * 32 + cc];
      const float v = xp[(size_t)cc * 1024 + t];
      o[cc >> 3].e[cc & 7] = (bf16)((v - mu) * wt + bs);
    }
    bf16* dst = xnt + (size_t)(b * 1024 + t) * 1024 + g * 32;
    #pragma unroll
    for (int j = 0; j < 4; ++j) *(bf16x8*)(dst + j * 8) = o[j].v;
  }
}

// ---------------------------------------------------------------------------
// Kernel 2/4: GEMM  C[m][n] = sum_k Aw[m][k] * Bt[n][k] (+bias[m]) (+res)
// Aw: fp32 weights (M x K) row-major, converted to bf16 in staging.
// Bt: bf16, B TRANSPOSED (N x K row-major) -> pure vector staging.
// Output bf16 (Cb) or fp32 (Cf with fp32 residual). Batched over blockIdx.z.
// 128x128 tile, BK=64, 4 waves 2x2 (wave tile 64x64 = 4x4 MFMA tiles).
// LDS row stride 72 elems = 144 B: 16B-aligned (b128-safe) and 2-way bank
// aliasing only (144/4=36 dwords; 36 mod 32 = 4 -> rows 8 apart collide;
// 2-way is free per m136).
// ---------------------------------------------------------------------------
__global__ __launch_bounds__(256) void gemm128_kernel(
    const float* __restrict__ Aw, const bf16* __restrict__ Bt,
    bf16* __restrict__ Cb, float* __restrict__ Cf,
    const float* __restrict__ bias, const float* __restrict__ resf,
    int M, int N, int K, long sBt, long sC)
{
  const int z = blockIdx.z;
  Bt += (size_t)z * sBt;
  const int n0 = blockIdx.x * 128, m0 = blockIdx.y * 128;

  __shared__ __align__(16) bf16 Al[128][72];   // [m][k]
  __shared__ __align__(16) bf16 Bl[128][72];   // [n][k]

  const int tid  = threadIdx.x;
  const int wave = tid >> 6, lane = tid & 63;
  const int quad = lane >> 4, l15 = lane & 15;
  const int wr = wave >> 1, wc = wave & 1;

  F4 acc[4][4];
  #pragma unroll
  for (int i = 0; i < 4; ++i)
    #pragma unroll
    for (int j = 0; j < 4; ++j) acc[i][j].v = (f32x4){0.f, 0.f, 0.f, 0.f};

  const int arow = tid >> 4, akc = (tid & 15) * 4;  // A: float4 per pass
  const int brow = tid >> 3, bkc = (tid & 7) * 8;   // B: bf16x8 per pass

  for (int k0 = 0; k0 < K; k0 += 64) {
    #pragma unroll
    for (int p = 0; p < 8; ++p) {                    // A: 128 rows x 64 k fp32
      const int r = arow + p * 16;
      const float4 a = *(const float4*)(Aw + (size_t)(m0 + r) * K + k0 + akc);
      B4 av;
      av.e[0] = (bf16)a.x; av.e[1] = (bf16)a.y;
      av.e[2] = (bf16)a.z; av.e[3] = (bf16)a.w;
      *(bf16x4*)&Al[r][akc] = av.v;
    }
    #pragma unroll
    for (int p = 0; p < 4; ++p) {                    // B: 128 rows x 64 k bf16
      const int r = brow + p * 32;
      *(bf16x8*)&Bl[r][bkc] =
          *(const bf16x8*)(Bt + (size_t)(n0 + r) * K + k0 + bkc);
    }
    __syncthreads();

    #pragma unroll
    for (int kk = 0; kk < 64; kk += 32) {
      bf16x8 af[4], bfr[4];
      #pragma unroll
      for (int mt = 0; mt < 4; ++mt)
        af[mt] = *(const bf16x8*)&Al[wr * 64 + mt * 16 + l15][kk + quad * 8];
      #pragma unroll
      for (int nt = 0; nt < 4; ++nt)
        bfr[nt] = *(const bf16x8*)&Bl[wc * 64 + nt * 16 + l15][kk + quad * 8];
      #pragma unroll
      for (int mt = 0; mt < 4; ++mt)
        #pragma unroll
        for (int nt = 0; nt < 4; ++nt)
          acc[mt][nt].v = __builtin_amdgcn_mfma_f32_16x16x32_bf16(
              af[mt], bfr[nt], acc[mt][nt].v, 0, 0, 0);
    }
    __syncthreads();
  }

  // Epilogue: C/D layout col(n)=l15, row(m)=quad*4+r
  bf16*  cb = Cb ? Cb + (size_t)z * sC : nullptr;
  float* cf = Cf ? Cf + (size_t)z * sC : nullptr;
  const float* rf = resf ? resf + (size_t)z * sC : nullptr;
  #pragma unroll
  for (int mt = 0; mt < 4; ++mt) {
    #pragma unroll
    for (int r = 0; r < 4; ++r) {
      const int m = m0 + wr * 64 + mt * 16 + quad * 4 + r;
      const float bb = bias[m];
      #pragma unroll
      for (int nt = 0; nt < 4; ++nt) {
        const int n = n0 + wc * 64 + nt * 16 + l15;
        float v = acc[mt][nt].e[r] + bb;
        if (rf) v += rf[(size_t)m * N + n];
        if (cf) cf[(size_t)m * N + n] = v;
        else    cb[(size_t)m * N + n] = (bf16)v;
      }
    }
  }
}

// ---------------------------------------------------------------------------
// Kernel 3: attention, batched over blockIdx.z (batch). qkv[b][o][t] bf16,
// o = h*192 + {0:q, 64:k, 128:v} + c. Output a^T[b*1024+t][c] bf16 directly
// from O^T registers (feeds the proj GEMM's Bt operand with no transpose).
// Flash-style online softmax over s-chunks of 64; wave w owns t rows
// [w*16, w*16+16). LDS stride 72 elems = 144 B (b128-aligned).
// ---------------------------------------------------------------------------
__global__ __launch_bounds__(256) void attn_kernel(
    const bf16* __restrict__ qkv, bf16* __restrict__ aout)
{
  const int tt = blockIdx.x, h = blockIdx.y, z = blockIdx.z;
  qkv  += (size_t)z * 3 * 1024 * 1024;
  aout += (size_t)z * 1024 * 1024;
  const int t0 = tt * 64;
  const size_t headbase = (size_t)(h * 192) * 1024;
  const bf16* qp = qkv + headbase;
  const bf16* kp = qkv + headbase + 64 * 1024;
  const bf16* vp = qkv + headbase + 128 * 1024;

  __shared__ __align__(16) bf16 qT[64][72];   // [t][c]
  __shared__ __align__(16) bf16 kT[64][72];   // [s][c]
  __shared__ __align__(16) bf16 Pl[64][72];   // [t][s]

  const int tid  = threadIdx.x;
  const int wave = tid >> 6, lane = tid & 63;
  const int quad = lane >> 4, l15 = lane & 15;

  {
    const int c = tid >> 2, to = (tid & 3) * 16;
    #pragma unroll
    for (int hh = 0; hh < 2; ++hh) {
      B8 u; u.v = *(const bf16x8*)(qp + (size_t)c * 1024 + t0 + to + hh * 8);
      #pragma unroll
      for (int j = 0; j < 8; ++j) qT[to + hh * 8 + j][c] = u.e[j];
    }
  }

  float m_i[4], l_i[4], alpha[4];
  #pragma unroll
  for (int r = 0; r < 4; ++r) { m_i[r] = -__builtin_inff(); l_i[r] = 0.f; }
  F4 oacc[4];
  #pragma unroll
  for (int ct = 0; ct < 4; ++ct) oacc[ct].v = (f32x4){0.f, 0.f, 0.f, 0.f};

  for (int s0 = 0; s0 < 1024; s0 += 64) {
    {
      const int c = tid >> 2, so = (tid & 3) * 16;
      #pragma unroll
      for (int hh = 0; hh < 2; ++hh) {
        B8 u; u.v = *(const bf16x8*)(kp + (size_t)c * 1024 + s0 + so + hh * 8);
        #pragma unroll
        for (int j = 0; j < 8; ++j) kT[so + hh * 8 + j][c] = u.e[j];
      }
    }
    __syncthreads();

    F4 sacc[4];
    #pragma unroll
    for (int st = 0; st < 4; ++st) sacc[st].v = (f32x4){0.f, 0.f, 0.f, 0.f};
    const bf16x8 aq0 = *(const bf16x8*)&qT[wave * 16 + l15][quad * 8];
    const bf16x8 aq1 = *(const bf16x8*)&qT[wave * 16 + l15][32 + quad * 8];
    #pragma unroll
    for (int st = 0; st < 4; ++st) {
      const bf16x8 bk0 = *(const bf16x8*)&kT[st * 16 + l15][quad * 8];
      const bf16x8 bk1 = *(const bf16x8*)&kT[st * 16 + l15][32 + quad * 8];
      sacc[st].v = __builtin_amdgcn_mfma_f32_16x16x32_bf16(aq0, bk0, sacc[st].v, 0, 0, 0);
      sacc[st].v = __builtin_amdgcn_mfma_f32_16x16x32_bf16(aq1, bk1, sacc[st].v, 0, 0, 0);
    }
    #pragma unroll
    for (int st = 0; st < 4; ++st)
      #pragma unroll
      for (int r = 0; r < 4; ++r) sacc[st].e[r] *= 0.125f;   // 1/sqrt(64)

    #pragma unroll
    for (int r = 0; r < 4; ++r) {
      float mx = fmaxf(fmaxf(sacc[0].e[r], sacc[1].e[r]),
                       fmaxf(sacc[2].e[r], sacc[3].e[r]));
      #pragma unroll
      for (int mk = 1; mk < 16; mk <<= 1) mx = fmaxf(mx, __shfl_xor(mx, mk));
      const float mnew = fmaxf(m_i[r], mx);
      float sum = 0.f;
      #pragma unroll
      for (int st = 0; st < 4; ++st) {
        const float p = __expf(sacc[st].e[r] - mnew);
        sacc[st].e[r] = p;
        sum += p;
      }
      #pragma unroll
      for (int mk = 1; mk < 16; mk <<= 1) sum += __shfl_xor(sum, mk);
      const float a = __expf(m_i[r] - mnew);
      l_i[r] = l_i[r] * a + sum;
      m_i[r] = mnew;
      alpha[r] = a;
    }
    #pragma unroll
    for (int ct = 0; ct < 4; ++ct)
      #pragma unroll
      for (int r = 0; r < 4; ++r) oacc[ct].e[r] *= alpha[r];

    #pragma unroll
    for (int st = 0; st < 4; ++st)
      #pragma unroll
      for (int r = 0; r < 4; ++r)
        Pl[wave * 16 + quad * 4 + r][st * 16 + l15] = (bf16)sacc[st].e[r];
    __syncthreads();

    #pragma unroll
    for (int ks = 0; ks < 2; ++ks) {
      const bf16x8 ap = *(const bf16x8*)&Pl[wave * 16 + l15][ks * 32 + quad * 8];
      #pragma unroll
      for (int ct = 0; ct < 4; ++ct) {
        const bf16x8 bv = *(const bf16x8*)(vp + (size_t)(ct * 16 + l15) * 1024
                                              + s0 + ks * 32 + quad * 8);
        oacc[ct].v = __builtin_amdgcn_mfma_f32_16x16x32_bf16(ap, bv, oacc[ct].v, 0, 0, 0);
      }
    }
    __syncthreads();
  }

  // Epilogue: write a^T[t][h*64 + c] straight from O^T (C/D layout:
  // t = t0 + wave*16 + quad*4 + r, c = ct*16 + l15). 32 B segments per quad.
  #pragma unroll
  for (int r = 0; r < 4; ++r) {
    const float inv = 1.f / l_i[r];
    const int t = t0 + wave * 16 + quad * 4 + r;
    #pragma unroll
    for (int ct = 0; ct < 4; ++ct)
      aout[(size_t)t * 1024 + h * 64 + ct * 16 + l15] = (bf16)(oacc[ct].e[r] * inv);
  }
}

// ---------------------------------------------------------------------------
// fp32 I/O; bf16 MFMA compute. rocprof showed the harness poisons ~256 MB of
// ws, so ws is large; batched plan uses 40 MB:
//   xnt [b][t][c] bf16 : ws[ 0,  8 MB)
//   qkv [b][o][t] bf16 : ws[ 8, 32 MB)
//   a^T [b][t][c] bf16 : ws[32, 40 MB)
// Fallback (ws < 40 MB): per-batch loop, xnt in d_out low half, 8 MB of ws.
// ---------------------------------------------------------------------------
extern "C" void kernel_launch(void* const* d_in, const int* in_sizes, int n_in,
                              void* d_out, int out_size, void* d_ws, size_t ws_size,
                              hipStream_t stream)
{
  const float* x    = (const float*)d_in[0];
  const float* nw   = (const float*)d_in[1];
  const float* nb   = (const float*)d_in[2];
  const float* qkvw = (const float*)d_in[3];
  const float* qkvb = (const float*)d_in[4];
  const float* pw   = (const float*)d_in[5];
  const float* pb   = (const float*)d_in[6];
  float* out = (float*)d_out;

  const long M1 = 1024L * 1024L;

  if (ws_size >= (size_t)40 * 1024 * 1024) {
    bf16* xnt = (bf16*)d_ws;                 // 4M elems
    bf16* qkv = xnt + 4 * M1;                // 12M elems
    bf16* at  = xnt + 16 * M1;               // 4M elems

    gn_t_kernel<<<dim3(128), dim3(256), 0, stream>>>(x, nw, nb, xnt);
    gemm128_kernel<<<dim3(8, 24, 4), dim3(256), 0, stream>>>(
        qkvw, xnt, qkv, nullptr, qkvb, nullptr, 3072, 1024, 1024, M1, 3 * M1);
    attn_kernel<<<dim3(16, 16, 4), dim3(256), 0, stream>>>(qkv, at);
    gemm128_kernel<<<dim3(8, 8, 4), dim3(256), 0, stream>>>(
        pw, at, nullptr, out, pb, x, 1024, 1024, 1024, M1, M1);
  } else {
    bf16* xnt  = (bf16*)d_out;               // 4M elems (low 8 MB of out)
    bf16* qkvB = (bf16*)d_ws;                // 3M elems
    bf16* atB  = qkvB + 3 * M1;              // 1M elems

    gn_t_kernel<<<dim3(128), dim3(256), 0, stream>>>(x, nw, nb, xnt);
    for (int b = 3; b >= 0; --b) {
      gemm128_kernel<<<dim3(8, 24, 1), dim3(256), 0, stream>>>(
          qkvw, xnt + (size_t)b * M1, qkvB, nullptr, qkvb, nullptr,
          3072, 1024, 1024, 0, 0);
      attn_kernel<<<dim3(16, 16, 1), dim3(256), 0, stream>>>(qkvB, atB);
      gemm128_kernel<<<dim3(8, 8, 1), dim3(256), 0, stream>>>(
          pw, atB, nullptr, out + (size_t)b * M1, pb, x + (size_t)b * M1,
          1024, 1024, 1024, 0, 0);
    }
  }
}

// Round 6
// 265.821 us; speedup vs baseline: 1.9701x; 1.0888x over previous
//
#include <hip/hip_runtime.h>
#include <hip/hip_bf16.h>

typedef __bf16 bf16;
typedef bf16  bf16x4 __attribute__((ext_vector_type(4)));
typedef bf16  bf16x8 __attribute__((ext_vector_type(8)));
typedef float f32x4  __attribute__((ext_vector_type(4)));

union B8 { bf16x8 v; bf16 e[8]; };
union B4 { bf16x4 v; bf16 e[4]; };
union F4 { f32x4 v; float e[4]; };

// ---------------------------------------------------------------------------
// Kernel 1: GroupNorm, transposed output: x[b][c][t] fp32 -> xnt[b][t][c] bf16.
// ---------------------------------------------------------------------------
__global__ __launch_bounds__(256) void gn_t_kernel(
    const float* __restrict__ x, const float* __restrict__ w,
    const float* __restrict__ bias, bf16* __restrict__ xnt)
{
  const int blk = blockIdx.x;
  const int b = blk >> 5, g = blk & 31;
  const float* xp = x + (size_t)(b * 1024 + g * 32) * 1024;
  const int tid = threadIdx.x;

  float s = 0.f, ss = 0.f;
  for (int ch = tid; ch < 4096; ch += 256) {
    const float4* p = (const float4*)(xp + (size_t)ch * 8);
    float4 u0 = p[0], u1 = p[1];
    s  += u0.x + u0.y + u0.z + u0.w + u1.x + u1.y + u1.z + u1.w;
    ss += u0.x*u0.x + u0.y*u0.y + u0.z*u0.z + u0.w*u0.w
        + u1.x*u1.x + u1.y*u1.y + u1.z*u1.z + u1.w*u1.w;
  }
  #pragma unroll
  for (int m = 1; m < 64; m <<= 1) { s += __shfl_xor(s, m); ss += __shfl_xor(ss, m); }

  __shared__ float red[8];
  __shared__ float stats[2];
  const int wave = tid >> 6, lane = tid & 63;
  if (lane == 0) { red[wave] = s; red[4 + wave] = ss; }
  __syncthreads();
  if (tid == 0) {
    float ts  = red[0] + red[1] + red[2] + red[3];
    float tss = red[4] + red[5] + red[6] + red[7];
    float mu  = ts * (1.f / 32768.f);
    float var = tss * (1.f / 32768.f) - mu * mu;
    stats[0] = mu;
    stats[1] = rsqrtf(var + 1e-5f);
  }
  __syncthreads();
  const float mu = stats[0], rs = stats[1];

  for (int ti = 0; ti < 4; ++ti) {
    const int t = ti * 256 + tid;
    B8 o[4];
    #pragma unroll
    for (int cc = 0; cc < 32; ++cc) {
      const float wt = w[g * 32 + cc] * rs;
      const float bs = bias[g * 32 + cc];
      const float v = xp[(size_t)cc * 1024 + t];
      o[cc >> 3].e[cc & 7] = (bf16)((v - mu) * wt + bs);
    }
    bf16* dst = xnt + (size_t)(b * 1024 + t) * 1024 + g * 32;
    #pragma unroll
    for (int j = 0; j < 4; ++j) *(bf16x8*)(dst + j * 8) = o[j].v;
  }
}

// ---------------------------------------------------------------------------
// Kernel 2a: qk^T GEMM.  qkT[b][t][n] = sum_c xnt[b][t][c]*W[bx*192+nl][c]+bias
// n in [0,2048): head = n>>7, j = n&127 -> W row = head*192 + j (covers q,k).
// Per block (bx = n-tile = head), W rows are CONTIGUOUS bx*192 .. +128.
// A = xnt (bf16, k-contiguous), B = W (fp32->bf16, k-contiguous): pure vector
// staging both sides. 128x128 tile, BK=64. LDS stride 72 (144 B, b128-safe).
// ---------------------------------------------------------------------------
__global__ __launch_bounds__(256) void gemm_qk_kernel(
    const bf16* __restrict__ xnt, const float* __restrict__ Wq,
    const float* __restrict__ bq, bf16* __restrict__ qkT)
{
  const int bx = blockIdx.x;              // n-tile == head index
  const int t0 = blockIdx.y * 128, z = blockIdx.z;
  const bf16* Ab = xnt + (size_t)z * 1024 * 1024;

  __shared__ __align__(16) bf16 Al[128][72];   // [t][c]
  __shared__ __align__(16) bf16 Bl[128][72];   // [n_loc][c]

  const int tid  = threadIdx.x;
  const int wave = tid >> 6, lane = tid & 63;
  const int quad = lane >> 4, l15 = lane & 15;
  const int wr = wave >> 1, wc = wave & 1;

  F4 acc[4][4];
  #pragma unroll
  for (int i = 0; i < 4; ++i)
    #pragma unroll
    for (int j = 0; j < 4; ++j) acc[i][j].v = (f32x4){0.f, 0.f, 0.f, 0.f};

  for (int k0 = 0; k0 < 1024; k0 += 64) {
    #pragma unroll
    for (int p = 0; p < 4; ++p) {            // A: 128 rows x 64 c, bf16x8
      const int r = (tid >> 3) + p * 32, ch = (tid & 7) * 8;
      *(bf16x8*)&Al[r][ch] = *(const bf16x8*)(Ab + (size_t)(t0 + r) * 1024 + k0 + ch);
    }
    #pragma unroll
    for (int p = 0; p < 8; ++p) {            // B: 128 W rows x 64 c fp32->bf16
      const int r = (tid >> 4) + p * 16, c4 = (tid & 15) * 4;
      const float4 a = *(const float4*)(Wq + (size_t)(bx * 192 + r) * 1024 + k0 + c4);
      B4 av;
      av.e[0] = (bf16)a.x; av.e[1] = (bf16)a.y;
      av.e[2] = (bf16)a.z; av.e[3] = (bf16)a.w;
      *(bf16x4*)&Bl[r][c4] = av.v;
    }
    __syncthreads();

    #pragma unroll
    for (int kk = 0; kk < 64; kk += 32) {
      bf16x8 af[4], bfr[4];
      #pragma unroll
      for (int mt = 0; mt < 4; ++mt)
        af[mt] = *(const bf16x8*)&Al[wr * 64 + mt * 16 + l15][kk + quad * 8];
      #pragma unroll
      for (int nt = 0; nt < 4; ++nt)
        bfr[nt] = *(const bf16x8*)&Bl[wc * 64 + nt * 16 + l15][kk + quad * 8];
      #pragma unroll
      for (int mt = 0; mt < 4; ++mt)
        #pragma unroll
        for (int nt = 0; nt < 4; ++nt)
          acc[mt][nt].v = __builtin_amdgcn_mfma_f32_16x16x32_bf16(
              af[mt], bfr[nt], acc[mt][nt].v, 0, 0, 0);
    }
    __syncthreads();
  }

  // C/D: row = t, col = n_loc. Write qkT[(z*1024+t)*2048 + bx*128 + n_loc].
  #pragma unroll
  for (int mt = 0; mt < 4; ++mt) {
    #pragma unroll
    for (int r = 0; r < 4; ++r) {
      const int t = t0 + wr * 64 + mt * 16 + quad * 4 + r;
      #pragma unroll
      for (int nt = 0; nt < 4; ++nt) {
        const int nl = wc * 64 + nt * 16 + l15;
        qkT[(size_t)(z * 1024 + t) * 2048 + bx * 128 + nl] =
            (bf16)(acc[mt][nt].e[r] + bq[bx * 192 + nl]);
      }
    }
  }
}

// ---------------------------------------------------------------------------
// Kernel 2b/4: GEMM  C[m][n] = sum_k Aw[rm(m)][k] * Bt[n][k] (+bias[rm(m)])
// (+res). vmap=1 remaps m to the V rows of the qkv weight: (m>>6)*192+128+
// (m&63). Output bf16 (Cb) or fp32 (Cf + fp32 residual). Batched over z.
// ---------------------------------------------------------------------------
__global__ __launch_bounds__(256) void gemm128_kernel(
    const float* __restrict__ Aw, const bf16* __restrict__ Bt,
    bf16* __restrict__ Cb, float* __restrict__ Cf,
    const float* __restrict__ bias, const float* __restrict__ resf,
    int N, int K, long sBt, long sC, int vmap)
{
  const int z = blockIdx.z;
  Bt += (size_t)z * sBt;
  const int n0 = blockIdx.x * 128, m0 = blockIdx.y * 128;

  __shared__ __align__(16) bf16 Al[128][72];
  __shared__ __align__(16) bf16 Bl[128][72];

  const int tid  = threadIdx.x;
  const int wave = tid >> 6, lane = tid & 63;
  const int quad = lane >> 4, l15 = lane & 15;
  const int wr = wave >> 1, wc = wave & 1;

  F4 acc[4][4];
  #pragma unroll
  for (int i = 0; i < 4; ++i)
    #pragma unroll
    for (int j = 0; j < 4; ++j) acc[i][j].v = (f32x4){0.f, 0.f, 0.f, 0.f};

  for (int k0 = 0; k0 < K; k0 += 64) {
    #pragma unroll
    for (int p = 0; p < 8; ++p) {
      const int r = (tid >> 4) + p * 16, c4 = (tid & 15) * 4;
      const int mg = m0 + r;
      const int wrow = vmap ? ((mg >> 6) * 192 + 128 + (mg & 63)) : mg;
      const float4 a = *(const float4*)(Aw + (size_t)wrow * K + k0 + c4);
      B4 av;
      av.e[0] = (bf16)a.x; av.e[1] = (bf16)a.y;
      av.e[2] = (bf16)a.z; av.e[3] = (bf16)a.w;
      *(bf16x4*)&Al[r][c4] = av.v;
    }
    #pragma unroll
    for (int p = 0; p < 4; ++p) {
      const int r = (tid >> 3) + p * 32, ch = (tid & 7) * 8;
      *(bf16x8*)&Bl[r][ch] = *(const bf16x8*)(Bt + (size_t)(n0 + r) * K + k0 + ch);
    }
    __syncthreads();

    #pragma unroll
    for (int kk = 0; kk < 64; kk += 32) {
      bf16x8 af[4], bfr[4];
      #pragma unroll
      for (int mt = 0; mt < 4; ++mt)
        af[mt] = *(const bf16x8*)&Al[wr * 64 + mt * 16 + l15][kk + quad * 8];
      #pragma unroll
      for (int nt = 0; nt < 4; ++nt)
        bfr[nt] = *(const bf16x8*)&Bl[wc * 64 + nt * 16 + l15][kk + quad * 8];
      #pragma unroll
      for (int mt = 0; mt < 4; ++mt)
        #pragma unroll
        for (int nt = 0; nt < 4; ++nt)
          acc[mt][nt].v = __builtin_amdgcn_mfma_f32_16x16x32_bf16(
              af[mt], bfr[nt], acc[mt][nt].v, 0, 0, 0);
    }
    __syncthreads();
  }

  bf16*  cb = Cb ? Cb + (size_t)z * sC : nullptr;
  float* cf = Cf ? Cf + (size_t)z * sC : nullptr;
  const float* rf = resf ? resf + (size_t)z * sC : nullptr;
  #pragma unroll
  for (int mt = 0; mt < 4; ++mt) {
    #pragma unroll
    for (int r = 0; r < 4; ++r) {
      const int m = m0 + wr * 64 + mt * 16 + quad * 4 + r;
      const float bb = bias[vmap ? ((m >> 6) * 192 + 128 + (m & 63)) : m];
      #pragma unroll
      for (int nt = 0; nt < 4; ++nt) {
        const int n = n0 + wc * 64 + nt * 16 + l15;
        float v = acc[mt][nt].e[r] + bb;
        if (rf) v += rf[(size_t)m * N + n];
        if (cf) cf[(size_t)m * N + n] = v;
        else    cb[(size_t)m * N + n] = (bf16)v;
      }
    }
  }
}

// ---------------------------------------------------------------------------
// Kernel 3: attention. Inputs: qkT[b][t][n] (n = h*128 + {0..63:q, 64..127:k})
// and v[b][ov][t] (ov = h*64+c). Everything staged with PURE VECTOR copies —
// the only scatter left is the P C->A layout round trip.
// blockIdx = (h, tt, z): h fastest => same-(h,z) t-tiles are 16 apart in
// linear ID -> same XCD under round-robin dispatch -> k/v L2 locality.
// Output a^T[b][t][c] written directly from O^T registers.
// ---------------------------------------------------------------------------
__global__ __launch_bounds__(256) void attn_kernel(
    const bf16* __restrict__ qkTin, const bf16* __restrict__ vmat,
    bf16* __restrict__ aout)
{
  const int h = blockIdx.x, tt = blockIdx.y, z = blockIdx.z;
  const bf16* qk = qkTin + (size_t)z * 1024 * 2048;
  const bf16* vp = vmat + (size_t)z * 1024 * 1024 + (size_t)(h * 64) * 1024;
  aout += (size_t)z * 1024 * 1024;
  const int t0 = tt * 64;

  __shared__ __align__(16) bf16 qT[64][72];   // [t][c]
  __shared__ __align__(16) bf16 kl[64][72];   // [s][c]
  __shared__ __align__(16) bf16 vl[64][72];   // [c][s]
  __shared__ __align__(16) bf16 Pl[64][72];   // [t][s]

  const int tid  = threadIdx.x;
  const int wave = tid >> 6, lane = tid & 63;
  const int quad = lane >> 4, l15 = lane & 15;
  const int srow = tid >> 2, soff = (tid & 3) * 16;   // shared staging coords

  // q tile: qk[(t0+r)*2048 + h*128 + 0..63] -> qT[r][c], vector copy
  *(bf16x8*)&qT[srow][soff] =
      *(const bf16x8*)(qk + (size_t)(t0 + srow) * 2048 + h * 128 + soff);
  *(bf16x8*)&qT[srow][soff + 8] =
      *(const bf16x8*)(qk + (size_t)(t0 + srow) * 2048 + h * 128 + soff + 8);

  float m_i[4], l_i[4], alpha[4];
  #pragma unroll
  for (int r = 0; r < 4; ++r) { m_i[r] = -__builtin_inff(); l_i[r] = 0.f; }
  F4 oacc[4];
  #pragma unroll
  for (int ct = 0; ct < 4; ++ct) oacc[ct].v = (f32x4){0.f, 0.f, 0.f, 0.f};

  for (int s0 = 0; s0 < 1024; s0 += 64) {
    // k tile: qk[(s0+r)*2048 + h*128+64 + c] -> kl[r][c]
    *(bf16x8*)&kl[srow][soff] =
        *(const bf16x8*)(qk + (size_t)(s0 + srow) * 2048 + h * 128 + 64 + soff);
    *(bf16x8*)&kl[srow][soff + 8] =
        *(const bf16x8*)(qk + (size_t)(s0 + srow) * 2048 + h * 128 + 64 + soff + 8);
    // v tile: vp[c*1024 + s0 + s] -> vl[c][s]
    *(bf16x8*)&vl[srow][soff] =
        *(const bf16x8*)(vp + (size_t)srow * 1024 + s0 + soff);
    *(bf16x8*)&vl[srow][soff + 8] =
        *(const bf16x8*)(vp + (size_t)srow * 1024 + s0 + soff + 8);
    __syncthreads();

    // S tile: wave's 16 t x 64 s, K=64 channels
    F4 sacc[4];
    #pragma unroll
    for (int st = 0; st < 4; ++st) sacc[st].v = (f32x4){0.f, 0.f, 0.f, 0.f};
    const bf16x8 aq0 = *(const bf16x8*)&qT[wave * 16 + l15][quad * 8];
    const bf16x8 aq1 = *(const bf16x8*)&qT[wave * 16 + l15][32 + quad * 8];
    #pragma unroll
    for (int st = 0; st < 4; ++st) {
      const bf16x8 bk0 = *(const bf16x8*)&kl[st * 16 + l15][quad * 8];
      const bf16x8 bk1 = *(const bf16x8*)&kl[st * 16 + l15][32 + quad * 8];
      sacc[st].v = __builtin_amdgcn_mfma_f32_16x16x32_bf16(aq0, bk0, sacc[st].v, 0, 0, 0);
      sacc[st].v = __builtin_amdgcn_mfma_f32_16x16x32_bf16(aq1, bk1, sacc[st].v, 0, 0, 0);
    }
    #pragma unroll
    for (int st = 0; st < 4; ++st)
      #pragma unroll
      for (int r = 0; r < 4; ++r) sacc[st].e[r] *= 0.125f;   // 1/sqrt(64)

    // Online softmax (row t = quad*4+r lives in this quad's 16 lanes)
    #pragma unroll
    for (int r = 0; r < 4; ++r) {
      float mx = fmaxf(fmaxf(sacc[0].e[r], sacc[1].e[r]),
                       fmaxf(sacc[2].e[r], sacc[3].e[r]));
      #pragma unroll
      for (int mk = 1; mk < 16; mk <<= 1) mx = fmaxf(mx, __shfl_xor(mx, mk));
      const float mnew = fmaxf(m_i[r], mx);
      float sum = 0.f;
      #pragma unroll
      for (int st = 0; st < 4; ++st) {
        const float p = __expf(sacc[st].e[r] - mnew);
        sacc[st].e[r] = p;
        sum += p;
      }
      #pragma unroll
      for (int mk = 1; mk < 16; mk <<= 1) sum += __shfl_xor(sum, mk);
      const float a = __expf(m_i[r] - mnew);
      l_i[r] = l_i[r] * a + sum;
      m_i[r] = mnew;
      alpha[r] = a;
    }
    #pragma unroll
    for (int ct = 0; ct < 4; ++ct)
      #pragma unroll
      for (int r = 0; r < 4; ++r) oacc[ct].e[r] *= alpha[r];

    // P: C-layout -> LDS -> A-layout
    #pragma unroll
    for (int st = 0; st < 4; ++st)
      #pragma unroll
      for (int r = 0; r < 4; ++r)
        Pl[wave * 16 + quad * 4 + r][st * 16 + l15] = (bf16)sacc[st].e[r];
    __syncthreads();

    // O^T[t][c] += P x v^T (B-frags from vl)
    #pragma unroll
    for (int ks = 0; ks < 2; ++ks) {
      const bf16x8 ap = *(const bf16x8*)&Pl[wave * 16 + l15][ks * 32 + quad * 8];
      #pragma unroll
      for (int ct = 0; ct < 4; ++ct) {
        const bf16x8 bv = *(const bf16x8*)&vl[ct * 16 + l15][ks * 32 + quad * 8];
        oacc[ct].v = __builtin_amdgcn_mfma_f32_16x16x32_bf16(ap, bv, oacc[ct].v, 0, 0, 0);
      }
    }
    __syncthreads();   // protect kl/vl/Pl before next chunk
  }

  // Write a^T[t][h*64+c] directly (t = t0+wave*16+quad*4+r, c = ct*16+l15)
  #pragma unroll
  for (int r = 0; r < 4; ++r) {
    const float inv = 1.f / l_i[r];
    const int t = t0 + wave * 16 + quad * 4 + r;
    #pragma unroll
    for (int ct = 0; ct < 4; ++ct)
      aout[(size_t)t * 1024 + h * 64 + ct * 16 + l15] = (bf16)(oacc[ct].e[r] * inv);
  }
}

// ---------------------------------------------------------------------------
// ws layout (harness poisons ~256 MB, r5 big path verified):
//   xnt [b][t][c] : ws[ 0,  8 MB)
//   qkT [b][t][n] : ws[ 8, 24 MB)   n in [0,2048) = per-head q,k channels
//   v   [b][ov][t]: ws[24, 32 MB)
//   a^T [b][t][c] : ws[32, 40 MB)
// ---------------------------------------------------------------------------
extern "C" void kernel_launch(void* const* d_in, const int* in_sizes, int n_in,
                              void* d_out, int out_size, void* d_ws, size_t ws_size,
                              hipStream_t stream)
{
  const float* x    = (const float*)d_in[0];
  const float* nw   = (const float*)d_in[1];
  const float* nb   = (const float*)d_in[2];
  const float* qkvw = (const float*)d_in[3];
  const float* qkvb = (const float*)d_in[4];
  const float* pw   = (const float*)d_in[5];
  const float* pb   = (const float*)d_in[6];
  float* out = (float*)d_out;

  const long M1 = 1024L * 1024L;
  bf16* xnt = (bf16*)d_ws;            // 4M elems
  bf16* qkT = xnt + 4 * M1;           // 8M elems
  bf16* vv  = xnt + 12 * M1;          // 4M elems
  bf16* at  = xnt + 16 * M1;          // 4M elems

  gn_t_kernel<<<dim3(128), dim3(256), 0, stream>>>(x, nw, nb, xnt);
  gemm_qk_kernel<<<dim3(16, 8, 4), dim3(256), 0, stream>>>(xnt, qkvw, qkvb, qkT);
  gemm128_kernel<<<dim3(8, 8, 4), dim3(256), 0, stream>>>(
      qkvw, xnt, vv, nullptr, qkvb, nullptr, 1024, 1024, M1, M1, 1);
  attn_kernel<<<dim3(16, 16, 4), dim3(256), 0, stream>>>(qkT, vv, at);
  gemm128_kernel<<<dim3(8, 8, 4), dim3(256), 0, stream>>>(
      pw, at, nullptr, out, pb, x, 1024, 1024, M1, M1, 0);
}

// Round 7
// 248.860 us; speedup vs baseline: 2.1044x; 1.0682x over previous
//
#include <hip/hip_runtime.h>
#include <hip/hip_bf16.h>

typedef __bf16 bf16;
typedef bf16  bf16x4 __attribute__((ext_vector_type(4)));
typedef bf16  bf16x8 __attribute__((ext_vector_type(8)));
typedef float f32x4  __attribute__((ext_vector_type(4)));

union B8 { bf16x8 v; bf16 e[8]; };
union B4 { bf16x4 v; bf16 e[4]; };
union F4 { f32x4 v; float e[4]; };

// ---------------------------------------------------------------------------
// Kernel 1: GroupNorm, transposed output: x[b][c][t] fp32 -> xnt[b][t][c] bf16.
// ---------------------------------------------------------------------------
__global__ __launch_bounds__(256) void gn_t_kernel(
    const float* __restrict__ x, const float* __restrict__ w,
    const float* __restrict__ bias, bf16* __restrict__ xnt)
{
  const int blk = blockIdx.x;
  const int b = blk >> 5, g = blk & 31;
  const float* xp = x + (size_t)(b * 1024 + g * 32) * 1024;
  const int tid = threadIdx.x;

  float s = 0.f, ss = 0.f;
  for (int ch = tid; ch < 4096; ch += 256) {
    const float4* p = (const float4*)(xp + (size_t)ch * 8);
    float4 u0 = p[0], u1 = p[1];
    s  += u0.x + u0.y + u0.z + u0.w + u1.x + u1.y + u1.z + u1.w;
    ss += u0.x*u0.x + u0.y*u0.y + u0.z*u0.z + u0.w*u0.w
        + u1.x*u1.x + u1.y*u1.y + u1.z*u1.z + u1.w*u1.w;
  }
  #pragma unroll
  for (int m = 1; m < 64; m <<= 1) { s += __shfl_xor(s, m); ss += __shfl_xor(ss, m); }

  __shared__ float red[8];
  __shared__ float stats[2];
  const int wave = tid >> 6, lane = tid & 63;
  if (lane == 0) { red[wave] = s; red[4 + wave] = ss; }
  __syncthreads();
  if (tid == 0) {
    float ts  = red[0] + red[1] + red[2] + red[3];
    float tss = red[4] + red[5] + red[6] + red[7];
    float mu  = ts * (1.f / 32768.f);
    float var = tss * (1.f / 32768.f) - mu * mu;
    stats[0] = mu;
    stats[1] = rsqrtf(var + 1e-5f);
  }
  __syncthreads();
  const float mu = stats[0], rs = stats[1];

  for (int ti = 0; ti < 4; ++ti) {
    const int t = ti * 256 + tid;
    B8 o[4];
    #pragma unroll
    for (int cc = 0; cc < 32; ++cc) {
      const float wt = w[g * 32 + cc] * rs;
      const float bs = bias[g * 32 + cc];
      const float v = xp[(size_t)cc * 1024 + t];
      o[cc >> 3].e[cc & 7] = (bf16)((v - mu) * wt + bs);
    }
    bf16* dst = xnt + (size_t)(b * 1024 + t) * 1024 + g * 32;
    #pragma unroll
    for (int j = 0; j < 4; ++j) *(bf16x8*)(dst + j * 8) = o[j].v;
  }
}

// ---------------------------------------------------------------------------
// Kernel 2a: qk^T GEMM -> qkT[b][t][n], n = head*128 + {0..63:q, 64..127:k}.
// Epilogue folds the attention scale 1/sqrt(sqrt(64)) = 0.35355339 into BOTH
// q and k channels (matches the reference's symmetric q*s, k*s scaling), so
// the attention kernel applies no scale at all.
// ---------------------------------------------------------------------------
__global__ __launch_bounds__(256) void gemm_qk_kernel(
    const bf16* __restrict__ xnt, const float* __restrict__ Wq,
    const float* __restrict__ bq, bf16* __restrict__ qkT)
{
  const int bx = blockIdx.x;              // n-tile == head index
  const int t0 = blockIdx.y * 128, z = blockIdx.z;
  const bf16* Ab = xnt + (size_t)z * 1024 * 1024;

  __shared__ __align__(16) bf16 Al[128][72];   // [t][c]
  __shared__ __align__(16) bf16 Bl[128][72];   // [n_loc][c]

  const int tid  = threadIdx.x;
  const int wave = tid >> 6, lane = tid & 63;
  const int quad = lane >> 4, l15 = lane & 15;
  const int wr = wave >> 1, wc = wave & 1;

  F4 acc[4][4];
  #pragma unroll
  for (int i = 0; i < 4; ++i)
    #pragma unroll
    for (int j = 0; j < 4; ++j) acc[i][j].v = (f32x4){0.f, 0.f, 0.f, 0.f};

  for (int k0 = 0; k0 < 1024; k0 += 64) {
    #pragma unroll
    for (int p = 0; p < 4; ++p) {            // A: 128 rows x 64 c, bf16x8
      const int r = (tid >> 3) + p * 32, ch = (tid & 7) * 8;
      *(bf16x8*)&Al[r][ch] = *(const bf16x8*)(Ab + (size_t)(t0 + r) * 1024 + k0 + ch);
    }
    #pragma unroll
    for (int p = 0; p < 8; ++p) {            // B: 128 W rows x 64 c fp32->bf16
      const int r = (tid >> 4) + p * 16, c4 = (tid & 15) * 4;
      const float4 a = *(const float4*)(Wq + (size_t)(bx * 192 + r) * 1024 + k0 + c4);
      B4 av;
      av.e[0] = (bf16)a.x; av.e[1] = (bf16)a.y;
      av.e[2] = (bf16)a.z; av.e[3] = (bf16)a.w;
      *(bf16x4*)&Bl[r][c4] = av.v;
    }
    __syncthreads();

    #pragma unroll
    for (int kk = 0; kk < 64; kk += 32) {
      bf16x8 af[4], bfr[4];
      #pragma unroll
      for (int mt = 0; mt < 4; ++mt)
        af[mt] = *(const bf16x8*)&Al[wr * 64 + mt * 16 + l15][kk + quad * 8];
      #pragma unroll
      for (int nt = 0; nt < 4; ++nt)
        bfr[nt] = *(const bf16x8*)&Bl[wc * 64 + nt * 16 + l15][kk + quad * 8];
      #pragma unroll
      for (int mt = 0; mt < 4; ++mt)
        #pragma unroll
        for (int nt = 0; nt < 4; ++nt)
          acc[mt][nt].v = __builtin_amdgcn_mfma_f32_16x16x32_bf16(
              af[mt], bfr[nt], acc[mt][nt].v, 0, 0, 0);
    }
    __syncthreads();
  }

  #pragma unroll
  for (int mt = 0; mt < 4; ++mt) {
    #pragma unroll
    for (int r = 0; r < 4; ++r) {
      const int t = t0 + wr * 64 + mt * 16 + quad * 4 + r;
      #pragma unroll
      for (int nt = 0; nt < 4; ++nt) {
        const int nl = wc * 64 + nt * 16 + l15;
        qkT[(size_t)(z * 1024 + t) * 2048 + bx * 128 + nl] =
            (bf16)((acc[mt][nt].e[r] + bq[bx * 192 + nl]) * 0.35355339f);
      }
    }
  }
}

// ---------------------------------------------------------------------------
// Kernel 2b/4: GEMM  C[m][n] = sum_k Aw[rm(m)][k] * Bt[n][k] (+bias[rm(m)])
// (+res). vmap=1 remaps m to the V rows of the qkv weight. Batched over z.
// ---------------------------------------------------------------------------
__global__ __launch_bounds__(256) void gemm128_kernel(
    const float* __restrict__ Aw, const bf16* __restrict__ Bt,
    bf16* __restrict__ Cb, float* __restrict__ Cf,
    const float* __restrict__ bias, const float* __restrict__ resf,
    int N, int K, long sBt, long sC, int vmap)
{
  const int z = blockIdx.z;
  Bt += (size_t)z * sBt;
  const int n0 = blockIdx.x * 128, m0 = blockIdx.y * 128;

  __shared__ __align__(16) bf16 Al[128][72];
  __shared__ __align__(16) bf16 Bl[128][72];

  const int tid  = threadIdx.x;
  const int wave = tid >> 6, lane = tid & 63;
  const int quad = lane >> 4, l15 = lane & 15;
  const int wr = wave >> 1, wc = wave & 1;

  F4 acc[4][4];
  #pragma unroll
  for (int i = 0; i < 4; ++i)
    #pragma unroll
    for (int j = 0; j < 4; ++j) acc[i][j].v = (f32x4){0.f, 0.f, 0.f, 0.f};

  for (int k0 = 0; k0 < K; k0 += 64) {
    #pragma unroll
    for (int p = 0; p < 8; ++p) {
      const int r = (tid >> 4) + p * 16, c4 = (tid & 15) * 4;
      const int mg = m0 + r;
      const int wrow = vmap ? ((mg >> 6) * 192 + 128 + (mg & 63)) : mg;
      const float4 a = *(const float4*)(Aw + (size_t)wrow * K + k0 + c4);
      B4 av;
      av.e[0] = (bf16)a.x; av.e[1] = (bf16)a.y;
      av.e[2] = (bf16)a.z; av.e[3] = (bf16)a.w;
      *(bf16x4*)&Al[r][c4] = av.v;
    }
    #pragma unroll
    for (int p = 0; p < 4; ++p) {
      const int r = (tid >> 3) + p * 32, ch = (tid & 7) * 8;
      *(bf16x8*)&Bl[r][ch] = *(const bf16x8*)(Bt + (size_t)(n0 + r) * K + k0 + ch);
    }
    __syncthreads();

    #pragma unroll
    for (int kk = 0; kk < 64; kk += 32) {
      bf16x8 af[4], bfr[4];
      #pragma unroll
      for (int mt = 0; mt < 4; ++mt)
        af[mt] = *(const bf16x8*)&Al[wr * 64 + mt * 16 + l15][kk + quad * 8];
      #pragma unroll
      for (int nt = 0; nt < 4; ++nt)
        bfr[nt] = *(const bf16x8*)&Bl[wc * 64 + nt * 16 + l15][kk + quad * 8];
      #pragma unroll
      for (int mt = 0; mt < 4; ++mt)
        #pragma unroll
        for (int nt = 0; nt < 4; ++nt)
          acc[mt][nt].v = __builtin_amdgcn_mfma_f32_16x16x32_bf16(
              af[mt], bfr[nt], acc[mt][nt].v, 0, 0, 0);
    }
    __syncthreads();
  }

  bf16*  cb = Cb ? Cb + (size_t)z * sC : nullptr;
  float* cf = Cf ? Cf + (size_t)z * sC : nullptr;
  const float* rf = resf ? resf + (size_t)z * sC : nullptr;
  #pragma unroll
  for (int mt = 0; mt < 4; ++mt) {
    #pragma unroll
    for (int r = 0; r < 4; ++r) {
      const int m = m0 + wr * 64 + mt * 16 + quad * 4 + r;
      const float bb = bias[vmap ? ((m >> 6) * 192 + 128 + (m & 63)) : m];
      #pragma unroll
      for (int nt = 0; nt < 4; ++nt) {
        const int n = n0 + wc * 64 + nt * 16 + l15;
        float v = acc[mt][nt].e[r] + bb;
        if (rf) v += rf[(size_t)m * N + n];
        if (cf) cf[(size_t)m * N + n] = v;
        else    cb[(size_t)m * N + n] = (bf16)v;
      }
    }
  }
}

// ---------------------------------------------------------------------------
// Kernel 3: attention, S^T formulation. Computes S^T = K Q^T (same LDS reads
// as Q K^T, operands swapped) so each lane holds 16 s-values of ONE t row
// (t = lane&15): softmax reductions are 15 in-register ops + 2 butterfly
// shuffles (xor16, xor32; quad copies bit-identical). m/l/alpha are per-lane
// scalars. P written as 4 x ds_write_b64 (lane owns 4 consecutive s per st).
// Pl rows are wave-private -> NO barrier between P write and PV read.
// qk channels pre-scaled by 0.35355 in the GEMM -> no scale here.
// ---------------------------------------------------------------------------
__global__ __launch_bounds__(256) void attn_kernel(
    const bf16* __restrict__ qkTin, const bf16* __restrict__ vmat,
    bf16* __restrict__ aout)
{
  const int h = blockIdx.x, tt = blockIdx.y, z = blockIdx.z;
  const bf16* qk = qkTin + (size_t)z * 1024 * 2048;
  const bf16* vp = vmat + (size_t)z * 1024 * 1024 + (size_t)(h * 64) * 1024;
  aout += (size_t)z * 1024 * 1024;
  const int t0 = tt * 64;

  __shared__ __align__(16) bf16 qT[64][72];   // [t][c]
  __shared__ __align__(16) bf16 kl[64][72];   // [s][c]
  __shared__ __align__(16) bf16 vl[64][72];   // [c][s]
  __shared__ __align__(16) bf16 Pl[64][72];   // [t][s], wave-private 16-row bands

  const int tid  = threadIdx.x;
  const int wave = tid >> 6, lane = tid & 63;
  const int quad = lane >> 4, l15 = lane & 15;
  const int srow = tid >> 2, soff = (tid & 3) * 16;

  // q tile (already scaled): vector copy
  *(bf16x8*)&qT[srow][soff] =
      *(const bf16x8*)(qk + (size_t)(t0 + srow) * 2048 + h * 128 + soff);
  *(bf16x8*)&qT[srow][soff + 8] =
      *(const bf16x8*)(qk + (size_t)(t0 + srow) * 2048 + h * 128 + soff + 8);

  float m_i = -__builtin_inff(), l_i = 0.f;   // per-lane, row t = l15
  F4 oacc[4];
  #pragma unroll
  for (int ct = 0; ct < 4; ++ct) oacc[ct].v = (f32x4){0.f, 0.f, 0.f, 0.f};

  for (int s0 = 0; s0 < 1024; s0 += 64) {
    *(bf16x8*)&kl[srow][soff] =
        *(const bf16x8*)(qk + (size_t)(s0 + srow) * 2048 + h * 128 + 64 + soff);
    *(bf16x8*)&kl[srow][soff + 8] =
        *(const bf16x8*)(qk + (size_t)(s0 + srow) * 2048 + h * 128 + 64 + soff + 8);
    *(bf16x8*)&vl[srow][soff] =
        *(const bf16x8*)(vp + (size_t)srow * 1024 + s0 + soff);
    *(bf16x8*)&vl[srow][soff + 8] =
        *(const bf16x8*)(vp + (size_t)srow * 1024 + s0 + soff + 8);
    __syncthreads();

    // S^T tile: D[s][t] = sum_c K[s][c] * Q^T[c][t]; A = k-frag, B = q-frag
    F4 sacc[4];
    #pragma unroll
    for (int st = 0; st < 4; ++st) sacc[st].v = (f32x4){0.f, 0.f, 0.f, 0.f};
    const bf16x8 bq0 = *(const bf16x8*)&qT[wave * 16 + l15][quad * 8];
    const bf16x8 bq1 = *(const bf16x8*)&qT[wave * 16 + l15][32 + quad * 8];
    #pragma unroll
    for (int st = 0; st < 4; ++st) {
      const bf16x8 ak0 = *(const bf16x8*)&kl[st * 16 + l15][quad * 8];
      const bf16x8 ak1 = *(const bf16x8*)&kl[st * 16 + l15][32 + quad * 8];
      sacc[st].v = __builtin_amdgcn_mfma_f32_16x16x32_bf16(ak0, bq0, sacc[st].v, 0, 0, 0);
      sacc[st].v = __builtin_amdgcn_mfma_f32_16x16x32_bf16(ak1, bq1, sacc[st].v, 0, 0, 0);
    }

    // Online softmax, row t = l15: lane holds s = s0 + st*16 + quad*4 + r
    float mx = sacc[0].e[0];
    #pragma unroll
    for (int st = 0; st < 4; ++st)
      #pragma unroll
      for (int r = 0; r < 4; ++r) mx = fmaxf(mx, sacc[st].e[r]);
    mx = fmaxf(mx, __shfl_xor(mx, 16));
    mx = fmaxf(mx, __shfl_xor(mx, 32));
    const float mnew = fmaxf(m_i, mx);
    float sum = 0.f;
    #pragma unroll
    for (int st = 0; st < 4; ++st)
      #pragma unroll
      for (int r = 0; r < 4; ++r) {
        const float p = __expf(sacc[st].e[r] - mnew);
        sacc[st].e[r] = p;
        sum += p;
      }
    sum += __shfl_xor(sum, 16);
    sum += __shfl_xor(sum, 32);
    const float alpha = __expf(m_i - mnew);
    l_i = l_i * alpha + sum;
    m_i = mnew;

    // Rescale O by alpha of its rows (t-local = quad*4+r, held by lane t)
    float av[4];
    #pragma unroll
    for (int r = 0; r < 4; ++r) av[r] = __shfl(alpha, quad * 4 + r);
    #pragma unroll
    for (int ct = 0; ct < 4; ++ct)
      #pragma unroll
      for (int r = 0; r < 4; ++r) oacc[ct].e[r] *= av[r];

    // P -> LDS A-layout: lane owns rows t=l15, 4 consecutive s per st
    #pragma unroll
    for (int st = 0; st < 4; ++st) {
      B4 pk;
      #pragma unroll
      for (int r = 0; r < 4; ++r) pk.e[r] = (bf16)sacc[st].e[r];
      *(bf16x4*)&Pl[wave * 16 + l15][st * 16 + quad * 4] = pk.v;
    }
    // No barrier: Pl band is wave-private; in-wave LDS ordering suffices.

    // O^T[t][c] += P x v^T
    #pragma unroll
    for (int ks = 0; ks < 2; ++ks) {
      const bf16x8 ap = *(const bf16x8*)&Pl[wave * 16 + l15][ks * 32 + quad * 8];
      #pragma unroll
      for (int ct = 0; ct < 4; ++ct) {
        const bf16x8 bv = *(const bf16x8*)&vl[ct * 16 + l15][ks * 32 + quad * 8];
        oacc[ct].v = __builtin_amdgcn_mfma_f32_16x16x32_bf16(ap, bv, oacc[ct].v, 0, 0, 0);
      }
    }
    __syncthreads();   // protect kl/vl before next chunk's staging
  }

  // Epilogue: a^T[t][h*64+c], t = t0+wave*16+quad*4+r, c = ct*16+l15
  const float inv = 1.f / l_i;
  float iv[4];
  #pragma unroll
  for (int r = 0; r < 4; ++r) iv[r] = __shfl(inv, quad * 4 + r);
  #pragma unroll
  for (int r = 0; r < 4; ++r) {
    const int t = t0 + wave * 16 + quad * 4 + r;
    #pragma unroll
    for (int ct = 0; ct < 4; ++ct)
      aout[(size_t)t * 1024 + h * 64 + ct * 16 + l15] = (bf16)(oacc[ct].e[r] * iv[r]);
  }
}

// ---------------------------------------------------------------------------
// ws layout:
//   xnt [b][t][c] : ws[ 0,  8 MB)
//   qkT [b][t][n] : ws[ 8, 24 MB)   n = head*128 + {q:0..63, k:64..127}
//   v   [b][ov][t]: ws[24, 32 MB)
//   a^T [b][t][c] : ws[32, 40 MB)
// ---------------------------------------------------------------------------
extern "C" void kernel_launch(void* const* d_in, const int* in_sizes, int n_in,
                              void* d_out, int out_size, void* d_ws, size_t ws_size,
                              hipStream_t stream)
{
  const float* x    = (const float*)d_in[0];
  const float* nw   = (const float*)d_in[1];
  const float* nb   = (const float*)d_in[2];
  const float* qkvw = (const float*)d_in[3];
  const float* qkvb = (const float*)d_in[4];
  const float* pw   = (const float*)d_in[5];
  const float* pb   = (const float*)d_in[6];
  float* out = (float*)d_out;

  const long M1 = 1024L * 1024L;
  bf16* xnt = (bf16*)d_ws;            // 4M elems
  bf16* qkT = xnt + 4 * M1;           // 8M elems
  bf16* vv  = xnt + 12 * M1;          // 4M elems
  bf16* at  = xnt + 16 * M1;          // 4M elems

  gn_t_kernel<<<dim3(128), dim3(256), 0, stream>>>(x, nw, nb, xnt);
  gemm_qk_kernel<<<dim3(16, 8, 4), dim3(256), 0, stream>>>(xnt, qkvw, qkvb, qkT);
  gemm128_kernel<<<dim3(8, 8, 4), dim3(256), 0, stream>>>(
      qkvw, xnt, vv, nullptr, qkvb, nullptr, 1024, 1024, M1, M1, 1);
  attn_kernel<<<dim3(16, 16, 4), dim3(256), 0, stream>>>(qkT, vv, at);
  gemm128_kernel<<<dim3(8, 8, 4), dim3(256), 0, stream>>>(
      pw, at, nullptr, out, pb, x, 1024, 1024, M1, M1, 0);
}

// Round 8
// 238.240 us; speedup vs baseline: 2.1982x; 1.0446x over previous
//
#include <hip/hip_runtime.h>
#include <hip/hip_bf16.h>

typedef __bf16 bf16;
typedef bf16  bf16x4 __attribute__((ext_vector_type(4)));
typedef bf16  bf16x8 __attribute__((ext_vector_type(8)));
typedef float f32x4  __attribute__((ext_vector_type(4)));

union B8 { bf16x8 v; bf16 e[8]; };
union B4 { bf16x4 v; bf16 e[4]; };
union F4 { f32x4 v; float e[4]; };

// ---------------------------------------------------------------------------
// Kernel 1: GroupNorm, transposed output: x[b][c][t] fp32 -> xnt[b][t][c] bf16.
// ---------------------------------------------------------------------------
__global__ __launch_bounds__(256) void gn_t_kernel(
    const float* __restrict__ x, const float* __restrict__ w,
    const float* __restrict__ bias, bf16* __restrict__ xnt)
{
  const int blk = blockIdx.x;
  const int b = blk >> 5, g = blk & 31;
  const float* xp = x + (size_t)(b * 1024 + g * 32) * 1024;
  const int tid = threadIdx.x;

  float s = 0.f, ss = 0.f;
  for (int ch = tid; ch < 4096; ch += 256) {
    const float4* p = (const float4*)(xp + (size_t)ch * 8);
    float4 u0 = p[0], u1 = p[1];
    s  += u0.x + u0.y + u0.z + u0.w + u1.x + u1.y + u1.z + u1.w;
    ss += u0.x*u0.x + u0.y*u0.y + u0.z*u0.z + u0.w*u0.w
        + u1.x*u1.x + u1.y*u1.y + u1.z*u1.z + u1.w*u1.w;
  }
  #pragma unroll
  for (int m = 1; m < 64; m <<= 1) { s += __shfl_xor(s, m); ss += __shfl_xor(ss, m); }

  __shared__ float red[8];
  __shared__ float stats[2];
  const int wave = tid >> 6, lane = tid & 63;
  if (lane == 0) { red[wave] = s; red[4 + wave] = ss; }
  __syncthreads();
  if (tid == 0) {
    float ts  = red[0] + red[1] + red[2] + red[3];
    float tss = red[4] + red[5] + red[6] + red[7];
    float mu  = ts * (1.f / 32768.f);
    float var = tss * (1.f / 32768.f) - mu * mu;
    stats[0] = mu;
    stats[1] = rsqrtf(var + 1e-5f);
  }
  __syncthreads();
  const float mu = stats[0], rs = stats[1];

  for (int ti = 0; ti < 4; ++ti) {
    const int t = ti * 256 + tid;
    B8 o[4];
    #pragma unroll
    for (int cc = 0; cc < 32; ++cc) {
      const float wt = w[g * 32 + cc] * rs;
      const float bs = bias[g * 32 + cc];
      const float v = xp[(size_t)cc * 1024 + t];
      o[cc >> 3].e[cc & 7] = (bf16)((v - mu) * wt + bs);
    }
    bf16* dst = xnt + (size_t)(b * 1024 + t) * 1024 + g * 32;
    #pragma unroll
    for (int j = 0; j < 4; ++j) *(bf16x8*)(dst + j * 8) = o[j].v;
  }
}

// ---------------------------------------------------------------------------
// Kernel 2: MERGED qkv GEMM — one dispatch over all 3072 weight rows.
// grid (24, 8, 4) = 768 blocks = 3 blocks/CU (the occupancy fix).
// D[t][wl] = sum_c xnt[t][c] * W[bx*128+wl][c]; per 16-wide output frag
// (base multiple of 16, type regions at 64-boundaries => frag type uniform):
//   base%192 <128 : q/k -> qkT[t][head*128 + base%192 + l15], (+bias)*0.35355
//   else          : v   -> vv[head*64 + base%192-128 + l15][t], +bias
// (v written transposed via scattered b16 stores; each block covers 128
//  consecutive t so L2 merges the lines.)
// ---------------------------------------------------------------------------
__global__ __launch_bounds__(256) void gemm_qkv_kernel(
    const bf16* __restrict__ xnt, const float* __restrict__ Wq,
    const float* __restrict__ bq, bf16* __restrict__ qkT, bf16* __restrict__ vv)
{
  const int bx = blockIdx.x;              // weight-row tile [bx*128, +128)
  const int t0 = blockIdx.y * 128, z = blockIdx.z;
  const bf16* Ab = xnt + (size_t)z * 1024 * 1024;

  __shared__ __align__(16) bf16 Al[128][72];   // [t][c]
  __shared__ __align__(16) bf16 Bl[128][72];   // [w-row local][c]

  const int tid  = threadIdx.x;
  const int wave = tid >> 6, lane = tid & 63;
  const int quad = lane >> 4, l15 = lane & 15;
  const int wr = wave >> 1, wc = wave & 1;

  F4 acc[4][4];
  #pragma unroll
  for (int i = 0; i < 4; ++i)
    #pragma unroll
    for (int j = 0; j < 4; ++j) acc[i][j].v = (f32x4){0.f, 0.f, 0.f, 0.f};

  for (int k0 = 0; k0 < 1024; k0 += 64) {
    #pragma unroll
    for (int p = 0; p < 4; ++p) {            // A: 128 t-rows x 64 c, bf16x8
      const int r = (tid >> 3) + p * 32, ch = (tid & 7) * 8;
      *(bf16x8*)&Al[r][ch] = *(const bf16x8*)(Ab + (size_t)(t0 + r) * 1024 + k0 + ch);
    }
    #pragma unroll
    for (int p = 0; p < 8; ++p) {            // B: 128 W rows x 64 c fp32->bf16
      const int r = (tid >> 4) + p * 16, c4 = (tid & 15) * 4;
      const float4 a = *(const float4*)(Wq + (size_t)(bx * 128 + r) * 1024 + k0 + c4);
      B4 av;
      av.e[0] = (bf16)a.x; av.e[1] = (bf16)a.y;
      av.e[2] = (bf16)a.z; av.e[3] = (bf16)a.w;
      *(bf16x4*)&Bl[r][c4] = av.v;
    }
    __syncthreads();

    #pragma unroll
    for (int kk = 0; kk < 64; kk += 32) {
      bf16x8 af[4], bfr[4];
      #pragma unroll
      for (int mt = 0; mt < 4; ++mt)
        af[mt] = *(const bf16x8*)&Al[wr * 64 + mt * 16 + l15][kk + quad * 8];
      #pragma unroll
      for (int nt = 0; nt < 4; ++nt)
        bfr[nt] = *(const bf16x8*)&Bl[wc * 64 + nt * 16 + l15][kk + quad * 8];
      #pragma unroll
      for (int mt = 0; mt < 4; ++mt)
        #pragma unroll
        for (int nt = 0; nt < 4; ++nt)
          acc[mt][nt].v = __builtin_amdgcn_mfma_f32_16x16x32_bf16(
              af[mt], bfr[nt], acc[mt][nt].v, 0, 0, 0);
    }
    __syncthreads();
  }

  #pragma unroll
  for (int nt = 0; nt < 4; ++nt) {
    const int base = bx * 128 + wc * 64 + nt * 16;   // global W row base of frag
    const int r192 = base % 192, head = base / 192;
    const float bb = bq[base + l15];
    if (r192 < 128) {                                // q or k channel
      const size_t col = head * 128 + r192 + l15;
      #pragma unroll
      for (int mt = 0; mt < 4; ++mt)
        #pragma unroll
        for (int r = 0; r < 4; ++r) {
          const int t = t0 + wr * 64 + mt * 16 + quad * 4 + r;
          qkT[(size_t)(z * 1024 + t) * 2048 + col] =
              (bf16)((acc[mt][nt].e[r] + bb) * 0.35355339f);
        }
    } else {                                         // v channel: transposed
      bf16* vrow = vv + ((size_t)z * 1024 + head * 64 + (r192 - 128) + l15) * 1024;
      #pragma unroll
      for (int mt = 0; mt < 4; ++mt)
        #pragma unroll
        for (int r = 0; r < 4; ++r) {
          const int t = t0 + wr * 64 + mt * 16 + quad * 4 + r;
          vrow[t] = (bf16)(acc[mt][nt].e[r] + bb);
        }
    }
  }
}

// ---------------------------------------------------------------------------
// Kernel 4: proj GEMM, 64x128 tiles for occupancy: grid (8,16,4) = 512 blocks
// = 2 blocks/CU. out[m][t] fp32 = sum_c pw[m][c]*at[t][c] + bias[m] + x[m][t].
// 4 waves 2x2, wave tile 32x64 (2x4 MFMA frags). LDS 27.6 KB.
// ---------------------------------------------------------------------------
__global__ __launch_bounds__(256) void gemm_proj_kernel(
    const float* __restrict__ Aw, const bf16* __restrict__ Bt,
    float* __restrict__ Cf, const float* __restrict__ bias,
    const float* __restrict__ resf)
{
  const int z = blockIdx.z;
  Bt   += (size_t)z * 1024 * 1024;
  Cf   += (size_t)z * 1024 * 1024;
  resf += (size_t)z * 1024 * 1024;
  const int n0 = blockIdx.x * 128, m0 = blockIdx.y * 64;

  __shared__ __align__(16) bf16 Al[64][72];    // [m][c]
  __shared__ __align__(16) bf16 Bl[128][72];   // [t][c]

  const int tid  = threadIdx.x;
  const int wave = tid >> 6, lane = tid & 63;
  const int quad = lane >> 4, l15 = lane & 15;
  const int wr = wave >> 1, wc = wave & 1;

  F4 acc[2][4];
  #pragma unroll
  for (int i = 0; i < 2; ++i)
    #pragma unroll
    for (int j = 0; j < 4; ++j) acc[i][j].v = (f32x4){0.f, 0.f, 0.f, 0.f};

  for (int k0 = 0; k0 < 1024; k0 += 64) {
    #pragma unroll
    for (int p = 0; p < 4; ++p) {            // A: 64 rows x 64 c fp32->bf16
      const int r = (tid >> 4) + p * 16, c4 = (tid & 15) * 4;
      const float4 a = *(const float4*)(Aw + (size_t)(m0 + r) * 1024 + k0 + c4);
      B4 av;
      av.e[0] = (bf16)a.x; av.e[1] = (bf16)a.y;
      av.e[2] = (bf16)a.z; av.e[3] = (bf16)a.w;
      *(bf16x4*)&Al[r][c4] = av.v;
    }
    #pragma unroll
    for (int p = 0; p < 4; ++p) {            // B: 128 t-rows x 64 c bf16
      const int r = (tid >> 3) + p * 32, ch = (tid & 7) * 8;
      *(bf16x8*)&Bl[r][ch] = *(const bf16x8*)(Bt + (size_t)(n0 + r) * 1024 + k0 + ch);
    }
    __syncthreads();

    #pragma unroll
    for (int kk = 0; kk < 64; kk += 32) {
      bf16x8 af[2], bfr[4];
      #pragma unroll
      for (int mt = 0; mt < 2; ++mt)
        af[mt] = *(const bf16x8*)&Al[wr * 32 + mt * 16 + l15][kk + quad * 8];
      #pragma unroll
      for (int nt = 0; nt < 4; ++nt)
        bfr[nt] = *(const bf16x8*)&Bl[wc * 64 + nt * 16 + l15][kk + quad * 8];
      #pragma unroll
      for (int mt = 0; mt < 2; ++mt)
        #pragma unroll
        for (int nt = 0; nt < 4; ++nt)
          acc[mt][nt].v = __builtin_amdgcn_mfma_f32_16x16x32_bf16(
              af[mt], bfr[nt], acc[mt][nt].v, 0, 0, 0);
    }
    __syncthreads();
  }

  #pragma unroll
  for (int mt = 0; mt < 2; ++mt) {
    #pragma unroll
    for (int r = 0; r < 4; ++r) {
      const int m = m0 + wr * 32 + mt * 16 + quad * 4 + r;
      const float bb = bias[m];
      #pragma unroll
      for (int nt = 0; nt < 4; ++nt) {
        const int n = n0 + wc * 64 + nt * 16 + l15;
        Cf[(size_t)m * 1024 + n] = acc[mt][nt].e[r] + bb + resf[(size_t)m * 1024 + n];
      }
    }
  }
}

// ---------------------------------------------------------------------------
// Kernel 3: attention, S^T formulation (unchanged from r7).
// ---------------------------------------------------------------------------
__global__ __launch_bounds__(256) void attn_kernel(
    const bf16* __restrict__ qkTin, const bf16* __restrict__ vmat,
    bf16* __restrict__ aout)
{
  const int h = blockIdx.x, tt = blockIdx.y, z = blockIdx.z;
  const bf16* qk = qkTin + (size_t)z * 1024 * 2048;
  const bf16* vp = vmat + (size_t)z * 1024 * 1024 + (size_t)(h * 64) * 1024;
  aout += (size_t)z * 1024 * 1024;
  const int t0 = tt * 64;

  __shared__ __align__(16) bf16 qT[64][72];   // [t][c]
  __shared__ __align__(16) bf16 kl[64][72];   // [s][c]
  __shared__ __align__(16) bf16 vl[64][72];   // [c][s]
  __shared__ __align__(16) bf16 Pl[64][72];   // [t][s], wave-private bands

  const int tid  = threadIdx.x;
  const int wave = tid >> 6, lane = tid & 63;
  const int quad = lane >> 4, l15 = lane & 15;
  const int srow = tid >> 2, soff = (tid & 3) * 16;

  *(bf16x8*)&qT[srow][soff] =
      *(const bf16x8*)(qk + (size_t)(t0 + srow) * 2048 + h * 128 + soff);
  *(bf16x8*)&qT[srow][soff + 8] =
      *(const bf16x8*)(qk + (size_t)(t0 + srow) * 2048 + h * 128 + soff + 8);

  float m_i = -__builtin_inff(), l_i = 0.f;
  F4 oacc[4];
  #pragma unroll
  for (int ct = 0; ct < 4; ++ct) oacc[ct].v = (f32x4){0.f, 0.f, 0.f, 0.f};

  for (int s0 = 0; s0 < 1024; s0 += 64) {
    *(bf16x8*)&kl[srow][soff] =
        *(const bf16x8*)(qk + (size_t)(s0 + srow) * 2048 + h * 128 + 64 + soff);
    *(bf16x8*)&kl[srow][soff + 8] =
        *(const bf16x8*)(qk + (size_t)(s0 + srow) * 2048 + h * 128 + 64 + soff + 8);
    *(bf16x8*)&vl[srow][soff] =
        *(const bf16x8*)(vp + (size_t)srow * 1024 + s0 + soff);
    *(bf16x8*)&vl[srow][soff + 8] =
        *(const bf16x8*)(vp + (size_t)srow * 1024 + s0 + soff + 8);
    __syncthreads();

    F4 sacc[4];
    #pragma unroll
    for (int st = 0; st < 4; ++st) sacc[st].v = (f32x4){0.f, 0.f, 0.f, 0.f};
    const bf16x8 bq0 = *(const bf16x8*)&qT[wave * 16 + l15][quad * 8];
    const bf16x8 bq1 = *(const bf16x8*)&qT[wave * 16 + l15][32 + quad * 8];
    #pragma unroll
    for (int st = 0; st < 4; ++st) {
      const bf16x8 ak0 = *(const bf16x8*)&kl[st * 16 + l15][quad * 8];
      const bf16x8 ak1 = *(const bf16x8*)&kl[st * 16 + l15][32 + quad * 8];
      sacc[st].v = __builtin_amdgcn_mfma_f32_16x16x32_bf16(ak0, bq0, sacc[st].v, 0, 0, 0);
      sacc[st].v = __builtin_amdgcn_mfma_f32_16x16x32_bf16(ak1, bq1, sacc[st].v, 0, 0, 0);
    }

    float mx = sacc[0].e[0];
    #pragma unroll
    for (int st = 0; st < 4; ++st)
      #pragma unroll
      for (int r = 0; r < 4; ++r) mx = fmaxf(mx, sacc[st].e[r]);
    mx = fmaxf(mx, __shfl_xor(mx, 16));
    mx = fmaxf(mx, __shfl_xor(mx, 32));
    const float mnew = fmaxf(m_i, mx);
    float sum = 0.f;
    #pragma unroll
    for (int st = 0; st < 4; ++st)
      #pragma unroll
      for (int r = 0; r < 4; ++r) {
        const float p = __expf(sacc[st].e[r] - mnew);
        sacc[st].e[r] = p;
        sum += p;
      }
    sum += __shfl_xor(sum, 16);
    sum += __shfl_xor(sum, 32);
    const float alpha = __expf(m_i - mnew);
    l_i = l_i * alpha + sum;
    m_i = mnew;

    float av[4];
    #pragma unroll
    for (int r = 0; r < 4; ++r) av[r] = __shfl(alpha, quad * 4 + r);
    #pragma unroll
    for (int ct = 0; ct < 4; ++ct)
      #pragma unroll
      for (int r = 0; r < 4; ++r) oacc[ct].e[r] *= av[r];

    #pragma unroll
    for (int st = 0; st < 4; ++st) {
      B4 pk;
      #pragma unroll
      for (int r = 0; r < 4; ++r) pk.e[r] = (bf16)sacc[st].e[r];
      *(bf16x4*)&Pl[wave * 16 + l15][st * 16 + quad * 4] = pk.v;
    }

    #pragma unroll
    for (int ks = 0; ks < 2; ++ks) {
      const bf16x8 ap = *(const bf16x8*)&Pl[wave * 16 + l15][ks * 32 + quad * 8];
      #pragma unroll
      for (int ct = 0; ct < 4; ++ct) {
        const bf16x8 bv = *(const bf16x8*)&vl[ct * 16 + l15][ks * 32 + quad * 8];
        oacc[ct].v = __builtin_amdgcn_mfma_f32_16x16x32_bf16(ap, bv, oacc[ct].v, 0, 0, 0);
      }
    }
    __syncthreads();
  }

  const float inv = 1.f / l_i;
  float iv[4];
  #pragma unroll
  for (int r = 0; r < 4; ++r) iv[r] = __shfl(inv, quad * 4 + r);
  #pragma unroll
  for (int r = 0; r < 4; ++r) {
    const int t = t0 + wave * 16 + quad * 4 + r;
    #pragma unroll
    for (int ct = 0; ct < 4; ++ct)
      aout[(size_t)t * 1024 + h * 64 + ct * 16 + l15] = (bf16)(oacc[ct].e[r] * iv[r]);
  }
}

// ---------------------------------------------------------------------------
// ws layout:
//   xnt [b][t][c] : ws[ 0,  8 MB)
//   qkT [b][t][n] : ws[ 8, 24 MB)   n = head*128 + {q:0..63, k:64..127}
//   v   [b][ov][t]: ws[24, 32 MB)
//   a^T [b][t][c] : ws[32, 40 MB)
// ---------------------------------------------------------------------------
extern "C" void kernel_launch(void* const* d_in, const int* in_sizes, int n_in,
                              void* d_out, int out_size, void* d_ws, size_t ws_size,
                              hipStream_t stream)
{
  const float* x    = (const float*)d_in[0];
  const float* nw   = (const float*)d_in[1];
  const float* nb   = (const float*)d_in[2];
  const float* qkvw = (const float*)d_in[3];
  const float* qkvb = (const float*)d_in[4];
  const float* pw   = (const float*)d_in[5];
  const float* pb   = (const float*)d_in[6];
  float* out = (float*)d_out;

  const long M1 = 1024L * 1024L;
  bf16* xnt = (bf16*)d_ws;            // 4M elems
  bf16* qkT = xnt + 4 * M1;           // 8M elems
  bf16* vv  = xnt + 12 * M1;          // 4M elems
  bf16* at  = xnt + 16 * M1;          // 4M elems

  gn_t_kernel<<<dim3(128), dim3(256), 0, stream>>>(x, nw, nb, xnt);
  gemm_qkv_kernel<<<dim3(24, 8, 4), dim3(256), 0, stream>>>(xnt, qkvw, qkvb, qkT, vv);
  attn_kernel<<<dim3(16, 16, 4), dim3(256), 0, stream>>>(qkT, vv, at);
  gemm_proj_kernel<<<dim3(8, 16, 4), dim3(256), 0, stream>>>(pw, at, out, pb, x);
}